// Round 26
// baseline (102.536 us; speedup 1.0000x reference)
//
#include <hip/hip_runtime.h>
#include <hip/hip_bf16.h>

// ---------- types ----------
typedef int   i4v  __attribute__((ext_vector_type(4)));
typedef int   i8v  __attribute__((ext_vector_type(8)));   // 8 VGPR MX operand
typedef float f16v __attribute__((ext_vector_type(16)));  // 32x32 accumulator

#define NUM_EMBEDS 8192
#define EMBED_DIM  256
#define BATCH      16
#define HW         1024
#define NVEC       (BATCH * HW)              // 16384
#define OUT0_ELEMS (BATCH * EMBED_DIM * HW)  // 4194304
#define NSPLIT     8                         // column splits (1 per XCD)
#define COLS_PER_S 1024                      // 8192 / NSPLIT
#define NTILES     32                        // COLS_PER_S / 32

// score bias: all biased scores positive -> u32 bit compare == float compare.
#define SCORE_BIAS 2097152.0f
// e8m0 scale 127 -> 2^0 = 1.0 in every byte: MX dequant is identity for any opsel
#define SCALE_ONE 0x7F7F7F7F

// ---------- workspace layout (ends ~6.5 MB — below proven-safe 13.2 MB) ----------
// eqF: FRAGMENT-MAJOR codebook fp8: [256 tiles][4 ks][64 lanes][32 B].
//   Wave load of tile g, slice ks = contiguous 2 KB at (g*4+ks)*2048 + lane*32.
//   Byte content per (ks,lane): cb_fp8[col = g*32 + (lane&31)][k = ks*64 + (lane>>5)*32 ..+32]
//   == exactly the bytes R16's LDS path delivered (same (ks,hi)->k map as A).
//   Layout verified on-HW in R23 (absmax matched R22 exactly).
#define WS_XQ   0              // 4 MB  fp8 x rows [16384][256]
#define WS_EQ   4194304        // 2 MB  fp8 codebook, fragment-major
#define WS_E2   6291456        // 32 KB biased e2*8192^2 (f32)
#define WS_AMIN 6324224        // 128 KB packed u64 (score_bits<<32 | col)

// pack 4 f32 -> 4 fp8 e4m3 bytes (RNE+sat, HW cvt)
static __device__ __forceinline__ unsigned pk_fp8x4(float a, float b, float c, float d) {
    int w = __builtin_amdgcn_cvt_pk_fp8_f32(a, b, 0, false);
    w = __builtin_amdgcn_cvt_pk_fp8_f32(c, d, w, true);
    return (unsigned)w;
}

// ---------- kernel 1: prep ----------
// z<16 : transpose x [16][256][1024] f32 -> xq [16384][256] fp8 (+init amin/out-loss slot)
// z==16: codebook f32 -> fp8 (x8192) fragment-major + biased e2*8192^2
__global__ void k_prep(const float* __restrict__ x, const float* __restrict__ cb,
                       unsigned char* __restrict__ xq, unsigned char* __restrict__ eqF,
                       float* __restrict__ e2, unsigned long long* __restrict__ amin,
                       float* __restrict__ out) {
    const int tx = threadIdx.x;          // 0..31
    const int ty = threadIdx.y;          // 0..7
    const int tid = ty * 32 + tx;        // 0..255

    if (blockIdx.z == 16) {
        const int bid = blockIdx.y * 32 + blockIdx.x;     // 0..255
        const int row = bid * 32 + (tid >> 3);            // codebook row (B col)
        const int sub = tid & 7;                          // 8 lanes per row
        const float4* src = reinterpret_cast<const float4*>(cb + (size_t)row * 256 + sub * 32);
        float s = 0.f;
        unsigned ou[8];
        #pragma unroll
        for (int i = 0; i < 4; ++i) {
            const float4 a = src[2 * i], b = src[2 * i + 1];
            s = fmaf(a.x, a.x, s); s = fmaf(a.y, a.y, s);
            s = fmaf(a.z, a.z, s); s = fmaf(a.w, a.w, s);
            s = fmaf(b.x, b.x, s); s = fmaf(b.y, b.y, s);
            s = fmaf(b.z, b.z, s); s = fmaf(b.w, b.w, s);
            ou[2 * i]     = pk_fp8x4(a.x * 8192.f, a.y * 8192.f, a.z * 8192.f, a.w * 8192.f);
            ou[2 * i + 1] = pk_fp8x4(b.x * 8192.f, b.y * 8192.f, b.z * 8192.f, b.w * 8192.f);
        }
        // fragment-major destination: k bytes sub*32..+31 == (ks = sub>>1, hi = sub&1)
        const size_t off = ((size_t)(row >> 5) * 4 + (sub >> 1)) * 2048
                         + (((sub & 1) << 5) | (row & 31)) * 32;
        uint4* dst = reinterpret_cast<uint4*>(eqF + off);
        dst[0] = make_uint4(ou[0], ou[1], ou[2], ou[3]);
        dst[1] = make_uint4(ou[4], ou[5], ou[6], ou[7]);
        s += __shfl_xor(s, 1, 64);
        s += __shfl_xor(s, 2, 64);
        s += __shfl_xor(s, 4, 64);
        if (sub == 0) e2[row] = fmaf(s, 67108864.0f, SCORE_BIAS);   // 8192^2 + bias
        return;
    }

    __shared__ float t[32][33];
    const int hw0 = blockIdx.x * 32;
    const int c0  = blockIdx.y * 32;
    const int b   = blockIdx.z;
    // fold init: 64 blocks x 256 threads cover the 16384 amin slots
    if (blockIdx.z == 0 && blockIdx.y < 2) {
        const int i = (blockIdx.y * 32 + blockIdx.x) * 256 + tid;
        amin[i] = ~0ULL;
        if (i == 0) out[OUT0_ELEMS] = 0.0f;   // loss accumulator (atomicAdd target)
    }
    #pragma unroll
    for (int i = 0; i < 4; ++i) {
        const int c = c0 + ty + i * 8;
        t[ty + i * 8][tx] = x[((b * EMBED_DIM + c) << 10) + hw0 + tx];
    }
    __syncthreads();
    // thread (tx,ty): 4 consecutive channels (c0+4ty..+3) of row hw0+tx -> one u32
    {
        const unsigned w = pk_fp8x4(t[ty * 4 + 0][tx], t[ty * 4 + 1][tx],
                                    t[ty * 4 + 2][tx], t[ty * 4 + 3][tx]);
        const int n = (b << 10) + hw0 + tx;
        *reinterpret_cast<unsigned*>(xq + (size_t)n * 256 + c0 + ty * 4) = w;
    }
}

// ---------- kernel 3: fused GEMM + argmin (MX fp8 32x32x64, BARRIER-FREE) ----------
// R23's kernel + amdgpu_waves_per_eu(2,2): pins the allocator's occupancy
// window to exactly 2 waves/EU -> VGPR budget 256/wave, defeating the
// heuristic that capped R23 at 128 and spilled (~190 live needed).
// Grid 512 = 64 row-blocks x 8 col-splits; s = blk&7 pins one 256KB
// fragment-major codebook slice per XCD (L2-resident). 256 thr = 4 waves,
// 64 rows/wave, A in regs. NO LDS, NO barriers, NO manual waitcnt: waves
// load their own B fragments register-direct (contiguous 2KB, coalesced),
// double-buffered named sets BA/BB, deferred-EPI X/Y alternation.
__global__ void __launch_bounds__(256)
__attribute__((amdgpu_waves_per_eu(2, 2)))
k_argmin(const unsigned char* __restrict__ xq, const unsigned char* __restrict__ eqF,
         const float* __restrict__ e2, unsigned long long* __restrict__ amin) {
    const int tid  = threadIdx.x;
    const int lane = tid & 63;
    const int w    = tid >> 6;           // wave 0..3
    const int l31  = lane & 31;
    const int hi   = lane >> 5;          // 0/1
    const int s    = blockIdx.x & 7;
    const int rb   = blockIdx.x >> 3;
    const int row0 = rb * 256;
    const int cb0  = s * COLS_PER_S;

    const char* xqB = (const char*)xq;
    const char* eqB = (const char*)eqF;

    // ---- A fragments straight from global: 64 rows/wave ----
    // 32x32x64 A map: lane row = l31 (+mr*32), k = ks*64 + hi*32 + byte (contiguous 32B)
    i8v afr[2][4];
    #pragma unroll
    for (int mr = 0; mr < 2; ++mr) {
        const int arow = row0 + w * 64 + mr * 32 + l31;
        const char* ap = xqB + ((size_t)arow << 8) + hi * 32;
        #pragma unroll
        for (int ks = 0; ks < 4; ++ks) {
            const i4v lo  = *reinterpret_cast<const i4v*>(ap + ks * 64);
            const i4v hi4 = *reinterpret_cast<const i4v*>(ap + ks * 64 + 16);
            afr[mr][ks] = (i8v){lo.x, lo.y, lo.z, lo.w, hi4.x, hi4.y, hi4.z, hi4.w};
        }
    }
    // pin A in registers (no sinking/rematerialization)
    #pragma unroll
    for (int mr = 0; mr < 2; ++mr)
        #pragma unroll
        for (int ks = 0; ks < 4; ++ks)
            asm volatile("" : "+v"(afr[mr][ks]));

    unsigned mu0[16], mu1[16];           // biased-score bits | (t<<5) | l31
    #pragma unroll
    for (int r = 0; r < 16; ++r) { mu0[r] = 0xFFFFFFFFu; mu1[r] = 0xFFFFFFFFu; }

    // LOADT(t): issue register loads of tile t's B fragments (+ its e2 value)
    auto LOADT = [&](int t, i8v* B, float& ev) {
        const char* bp = eqB + ((size_t)((s * 32 + t) * 4) * 2048) + lane * 32;
        #pragma unroll
        for (int ks = 0; ks < 4; ++ks) {
            const i4v lo  = *reinterpret_cast<const i4v*>(bp + ks * 2048);
            const i4v hi4 = *reinterpret_cast<const i4v*>(bp + ks * 2048 + 16);
            B[ks] = (i8v){lo.x, lo.y, lo.z, lo.w, hi4.x, hi4.y, hi4.z, hi4.w};
        }
        ev = e2[cb0 + t * 32 + l31];
    };

    // BURST: 8 MFMAs of one tile from a named B set into fresh accs
    auto BURST = [&](const i8v* B, f16v& c0v, f16v& c1v) {
        c0v = (f16v){}; c1v = (f16v){};
        __builtin_amdgcn_s_setprio(1);
        #pragma unroll
        for (int ks = 0; ks < 4; ++ks) {
            c0v = __builtin_amdgcn_mfma_scale_f32_32x32x64_f8f6f4(
                      afr[0][ks], B[ks], c0v, 0, 0, 0, SCALE_ONE, 0, SCALE_ONE);
            c1v = __builtin_amdgcn_mfma_scale_f32_32x32x64_f8f6f4(
                      afr[1][ks], B[ks], c1v, 0, 0, 0, SCALE_ONE, 0, SCALE_ONE);
        }
        __builtin_amdgcn_s_setprio(0);
    };

    // EPI: biased score = bias + 8192^2*e2 - 16384*acc (positive, u32-orderable);
    // low 10 mantissa bits replaced by (t<<5)|l31 (perturbation << fp8 noise)
    auto EPI = [&](const f16v& c0v, const f16v& c1v, float evS, unsigned orvS) {
        #pragma unroll
        for (int r = 0; r < 16; ++r) {
            const float s0 = fmaf(-16384.0f, c0v[r], evS);
            mu0[r] = min(mu0[r], (__float_as_uint(s0) & 0xFFFFFC00u) | orvS);
            const float s1 = fmaf(-16384.0f, c1v[r], evS);
            mu1[r] = min(mu1[r], (__float_as_uint(s1) & 0xFFFFFC00u) | orvS);
        }
    };

    // 2-deep pipeline, all named sets (rule #20), NTILES = 32 (even)
    i8v BA[4], BB[4];
    float evLa, evLb;                    // ev of most-recently-loaded tile per set
    f16v xA0, xA1, yB0, yB1;
    float evX, evY; unsigned orvX, orvY;

    LOADT(0, BA, evLa);
    LOADT(1, BB, evLb);
    evX = evLa; orvX = (unsigned)((0 << 5) | l31);
    BURST(BA, xA0, xA1);
    for (int t = 1; t < NTILES - 1; t += 2) {
        LOADT(t + 1, BA, evLa);
        evY = evLb; orvY = (unsigned)((t << 5) | l31);
        BURST(BB, yB0, yB1);
        EPI(xA0, xA1, evX, orvX);
        LOADT(t + 2, BB, evLb);
        evX = evLa; orvX = (unsigned)(((t + 1) << 5) | l31);
        BURST(BA, xA0, xA1);
        EPI(yB0, yB1, evY, orvY);
    }
    evY = evLb; orvY = (unsigned)(((NTILES - 1) << 5) | l31);
    BURST(BB, yB0, yB1);
    EPI(xA0, xA1, evX, orvX);
    EPI(yB0, yB1, evY, orvY);

    // ---- reduce over 32 col-lanes (butterfly min_u32), then atomicMin ----
    #pragma unroll
    for (int mr = 0; mr < 2; ++mr)
        #pragma unroll
        for (int r = 0; r < 16; ++r) {
            unsigned u = mr ? mu1[r] : mu0[r];
            #pragma unroll
            for (int m = 1; m <= 16; m <<= 1)
                u = min(u, (unsigned)__shfl_xor((int)u, m, 64));
            if (l31 == 0) {
                const int row_g = row0 + w * 64 + mr * 32 + (r & 3) + 8 * (r >> 2) + 4 * hi;
                const int col = cb0 + (int)(u & 1023u);   // (t<<5)|l31 == local col
                const unsigned long long key = ((unsigned long long)u << 32) | (unsigned)col;
                atomicMin(&amin[row_g], key);
            }
        }
}

// ---------- kernel 4: gather + straight-through output + loss ----------
// Loss is linear in block partials: each block atomicAdds its scaled partial
// directly into out[OUT0_ELEMS] (zeroed by k_prep). No fence/ticket/finalize.
__global__ void __launch_bounds__(256)
k_gather_loss(const float* __restrict__ x, const float* __restrict__ cb,
              const unsigned long long* __restrict__ amin, float* __restrict__ out) {
    __shared__ float q[32][257];
    __shared__ int e_s[32];
    const int tid = threadIdx.x;
    const int hw0 = (blockIdx.x & 31) * 32;
    const int b   = blockIdx.x >> 5;
    const int n0  = (b << 10) + hw0;
    if (tid < 32) e_s[tid] = (int)(amin[n0 + tid] & 0xFFFFFFFFu);
    __syncthreads();
    #pragma unroll 8
    for (int r = 0; r < 32; ++r)
        q[r][tid] = cb[(size_t)e_s[r] * EMBED_DIM + tid];
    __syncthreads();
    const int tx = tid & 31;    // hw offset within tile
    const int ty = tid >> 5;    // 0..7  (channel group)
    float sum = 0.f;
    #pragma unroll
    for (int i = 0; i < 32; ++i) {
        const int c = ty * 32 + i;
        const float qv = q[tx][c];
        const int o = ((b * EMBED_DIM + c) << 10) + hw0 + tx;
        const float xv = x[o];
        out[o] = qv;
        const float d = qv - xv;
        sum = fmaf(d, d, sum);
    }
    #pragma unroll
    for (int off = 32; off > 0; off >>= 1) sum += __shfl_down(sum, off, 64);
    __shared__ float ls[4];
    const int lane = tid & 63, wid = tid >> 6;
    if (lane == 0) ls[wid] = sum;
    __syncthreads();
    if (tid == 0)
        atomicAdd(out + OUT0_ELEMS,
                  (ls[0] + ls[1] + ls[2] + ls[3]) * (1.25f / (float)OUT0_ELEMS));
}

extern "C" void kernel_launch(void* const* d_in, const int* in_sizes, int n_in,
                              void* d_out, int out_size, void* d_ws, size_t ws_size,
                              hipStream_t stream) {
    const float* x  = (const float*)d_in[0];
    const float* cb = (const float*)d_in[1];
    float* out = (float*)d_out;

    char* ws = (char*)d_ws;
    unsigned char* xq = (unsigned char*)(ws + WS_XQ);
    unsigned char* eqF = (unsigned char*)(ws + WS_EQ);
    float* e2 = (float*)(ws + WS_E2);
    unsigned long long* amin = (unsigned long long*)(ws + WS_AMIN);

    k_prep<<<dim3(32, 8, 17), dim3(32, 8, 1), 0, stream>>>(x, cb, xq, eqF, e2, amin, out);
    k_argmin<<<dim3(64 * NSPLIT), dim3(256), 0, stream>>>(xq, eqF, e2, amin);
    k_gather_loss<<<dim3(512), dim3(256), 0, stream>>>(x, cb, amin, out);
}

// Round 27
// 64.745 us; speedup vs baseline: 1.5837x; 1.5837x over previous
//
#include <hip/hip_runtime.h>
#include <hip/hip_bf16.h>

// ---------- types ----------
typedef int   i4v  __attribute__((ext_vector_type(4)));
typedef int   i8v  __attribute__((ext_vector_type(8)));   // 8 VGPR MX operand
typedef float f16v __attribute__((ext_vector_type(16)));  // 32x32 accumulator

#define NUM_EMBEDS 8192
#define EMBED_DIM  256
#define BATCH      16
#define HW         1024
#define NVEC       (BATCH * HW)              // 16384
#define OUT0_ELEMS (BATCH * EMBED_DIM * HW)  // 4194304
#define NSPLIT     8                         // column splits (1 per XCD)
#define COLS_PER_S 1024                      // 8192 / NSPLIT
#define NTILES     32                        // COLS_PER_S / 32

// k_argmin LDS map (dynamic, 28 KiB; 2 blocks/CU = 56 KiB):
//   buf0/1/2 @ 0,8192,16384  B tile [32 cols][256B] fp8, LINEAR rows
//     (gload_lds dest). 16B chunks XOR-swizzled in the GLOBAL SOURCE:
//     LDS[r][c] holds G[r][c^(r&7)]; read applies the same XOR (involution).
//   e2  @ 24576  this block's 1024 biased-scaled e2 floats (4 KiB)
#define BUFB  8192
#define E2L   24576
#define SMEM3 28672

// score bias: all biased scores positive -> u32 bit compare == float compare.
#define SCORE_BIAS 2097152.0f
// e8m0 scale 127 -> 2^0 = 1.0 in every byte: MX dequant is identity for any opsel
#define SCALE_ONE 0x7F7F7F7F

// ---------- workspace layout (ends ~6.5 MB — below proven-safe 13.2 MB) ----------
#define WS_XQ   0              // 4 MB  fp8 x rows [16384][256]
#define WS_EQ   4194304        // 2 MB  fp8 codebook x8192 [8192][256]
#define WS_E2   6291456        // 32 KB biased e2*8192^2 (f32)
#define WS_AMIN 6324224        // 128 KB packed u64 (score_bits<<32 | col)

static __device__ __forceinline__ void gload_lds16(const void* g, void* l) {
    __builtin_amdgcn_global_load_lds(
        (const __attribute__((address_space(1))) unsigned int*)g,
        (__attribute__((address_space(3))) unsigned int*)l, 16, 0, 0);
}

// pack 4 f32 -> 4 fp8 e4m3 bytes (RNE+sat, HW cvt)
static __device__ __forceinline__ unsigned pk_fp8x4(float a, float b, float c, float d) {
    int w = __builtin_amdgcn_cvt_pk_fp8_f32(a, b, 0, false);
    w = __builtin_amdgcn_cvt_pk_fp8_f32(c, d, w, true);
    return (unsigned)w;
}

// ---------- kernel 1: prep ----------
// z<16 : transpose x [16][256][1024] f32 -> xq [16384][256] fp8 (+init amin/out-loss slot)
// z==16: codebook f32 -> fp8 (x8192) + biased e2*8192^2
__global__ void k_prep(const float* __restrict__ x, const float* __restrict__ cb,
                       unsigned char* __restrict__ xq, unsigned char* __restrict__ eq,
                       float* __restrict__ e2, unsigned long long* __restrict__ amin,
                       float* __restrict__ out) {
    const int tx = threadIdx.x;          // 0..31
    const int ty = threadIdx.y;          // 0..7
    const int tid = ty * 32 + tx;        // 0..255

    if (blockIdx.z == 16) {
        const int bid = blockIdx.y * 32 + blockIdx.x;     // 0..255
        const int row = bid * 32 + (tid >> 3);            // codebook row
        const int sub = tid & 7;                          // 8 lanes per row
        const float4* src = reinterpret_cast<const float4*>(cb + (size_t)row * 256 + sub * 32);
        float s = 0.f;
        unsigned ou[8];
        #pragma unroll
        for (int i = 0; i < 4; ++i) {
            const float4 a = src[2 * i], b = src[2 * i + 1];
            s = fmaf(a.x, a.x, s); s = fmaf(a.y, a.y, s);
            s = fmaf(a.z, a.z, s); s = fmaf(a.w, a.w, s);
            s = fmaf(b.x, b.x, s); s = fmaf(b.y, b.y, s);
            s = fmaf(b.z, b.z, s); s = fmaf(b.w, b.w, s);
            ou[2 * i]     = pk_fp8x4(a.x * 8192.f, a.y * 8192.f, a.z * 8192.f, a.w * 8192.f);
            ou[2 * i + 1] = pk_fp8x4(b.x * 8192.f, b.y * 8192.f, b.z * 8192.f, b.w * 8192.f);
        }
        uint4* dst = reinterpret_cast<uint4*>(eq + (size_t)row * 256 + sub * 32);
        dst[0] = make_uint4(ou[0], ou[1], ou[2], ou[3]);
        dst[1] = make_uint4(ou[4], ou[5], ou[6], ou[7]);
        s += __shfl_xor(s, 1, 64);
        s += __shfl_xor(s, 2, 64);
        s += __shfl_xor(s, 4, 64);
        if (sub == 0) e2[row] = fmaf(s, 67108864.0f, SCORE_BIAS);   // 8192^2 + bias
        return;
    }

    __shared__ float t[32][33];
    const int hw0 = blockIdx.x * 32;
    const int c0  = blockIdx.y * 32;
    const int b   = blockIdx.z;
    // fold init: 64 blocks x 256 threads cover the 16384 amin slots
    if (blockIdx.z == 0 && blockIdx.y < 2) {
        const int i = (blockIdx.y * 32 + blockIdx.x) * 256 + tid;
        amin[i] = ~0ULL;
        if (i == 0) out[OUT0_ELEMS] = 0.0f;   // loss accumulator (atomicAdd target)
    }
    #pragma unroll
    for (int i = 0; i < 4; ++i) {
        const int c = c0 + ty + i * 8;
        t[ty + i * 8][tx] = x[((b * EMBED_DIM + c) << 10) + hw0 + tx];
    }
    __syncthreads();
    // thread (tx,ty): 4 consecutive channels (c0+4ty..+3) of row hw0+tx -> one u32
    {
        const unsigned w = pk_fp8x4(t[ty * 4 + 0][tx], t[ty * 4 + 1][tx],
                                    t[ty * 4 + 2][tx], t[ty * 4 + 3][tx]);
        const int n = (b << 10) + hw0 + tx;
        *reinterpret_cast<unsigned*>(xq + (size_t)n * 256 + c0 + ty * 4) = w;
    }
}

// ---------- kernel 3: fused GEMM + argmin (MX fp8 32x32x64, deferred epilogue) ----------
// R16's proven kernel, verbatim (44.0 µs, VGPR 120, no spill): grid 512 =
// 64 row-blocks x 8 col-splits, XCD-pinned 256KB codebook slices, 256 thr =
// 4 waves, 64 rows/wave, 3 LDS buffers + counted vmcnt(2), T15-style 2-phase
// deferred epilogue with named accumulator sets, biased-u32 min epilogue.
__global__ void __launch_bounds__(256, 2)
k_argmin(const unsigned char* __restrict__ xq, const unsigned char* __restrict__ eq,
         const float* __restrict__ e2, unsigned long long* __restrict__ amin) {
    extern __shared__ char smem[];
    const int tid  = threadIdx.x;
    const int lane = tid & 63;
    const int w    = tid >> 6;           // wave 0..3
    const int l31  = lane & 31;
    const int hi   = lane >> 5;          // 0/1
    const int s    = blockIdx.x & 7;
    const int rb   = blockIdx.x >> 3;
    const int row0 = rb * 256;
    const int cb0  = s * COLS_PER_S;

    const char* xqB = (const char*)xq;
    const char* eqB = (const char*)eq;
    const char* e2B = (const char*)e2;

    // ---- A fragments straight from global: 64 rows/wave ----
    // 32x32x64 A map: lane row = l31 (+mr*32), k = ks*64 + hi*32 + byte (contiguous 32B)
    i8v afr[2][4];
    #pragma unroll
    for (int mr = 0; mr < 2; ++mr) {
        const int arow = row0 + w * 64 + mr * 32 + l31;
        const char* ap = xqB + ((size_t)arow << 8) + hi * 32;
        #pragma unroll
        for (int ks = 0; ks < 4; ++ks) {
            const i4v lo  = *reinterpret_cast<const i4v*>(ap + ks * 64);
            const i4v hi4 = *reinterpret_cast<const i4v*>(ap + ks * 64 + 16);
            afr[mr][ks] = (i8v){lo.x, lo.y, lo.z, lo.w, hi4.x, hi4.y, hi4.z, hi4.w};
        }
    }

    // ---- e2 slice (4 KiB): each wave stages 1 KiB ----
    gload_lds16(e2B + ((size_t)cb0 << 2) + w * 1024 + lane * 16,
                smem + E2L + w * 1024);

    // ---- B staging: gload_lds direct, LDS linear [32][256], source-swizzled ----
    // instr p = w*2+j covers rows 4p..4p+3 (1 KiB). HW dest = base + lane*16:
    // lane -> row 4p+(lane>>4), chunk lane&15. Source supplies G[r][c^(r&7)].
    auto STAGE = [&](int tci, int lds_off) {
        #pragma unroll
        for (int j = 0; j < 2; ++j) {
            const int p = w * 2 + j;
            const int r = 4 * p + (lane >> 4);
            const int c = (lane & 15) ^ (r & 7);
            gload_lds16(eqB + ((size_t)(cb0 + tci * 32 + r) << 8) + (c << 4),
                        smem + lds_off + p * 1024);
        }
    };
    STAGE(0, 0);
    STAGE(1, BUFB);

    // pin A in registers (no sinking/rematerialization)
    #pragma unroll
    for (int mr = 0; mr < 2; ++mr)
        #pragma unroll
        for (int ks = 0; ks < 4; ++ks)
            asm volatile("" : "+v"(afr[mr][ks]));

    unsigned mu0[16], mu1[16];           // biased-score bits | (t<<5) | l31
    #pragma unroll
    for (int r = 0; r < 16; ++r) { mu0[r] = 0xFFFFFFFFu; mu1[r] = 0xFFFFFFFFu; }

    const int sx = l31 & 7;              // read-side XOR (matches source swizzle)

    // PHASE(t): sync+stage for tile t, then MFMA burst into c0/c1 (fresh accs)
    auto PHASE = [&](int t, f16v& c0v, f16v& c1v, float& evS, unsigned& orvS) {
        if (t < NTILES - 1) {
            asm volatile("s_waitcnt vmcnt(2)" ::: "memory");
        } else {
            asm volatile("s_waitcnt vmcnt(0)" ::: "memory");
        }
        __builtin_amdgcn_s_barrier();    // tile t landed; all waves done reading
                                         // the buffer STAGE(t+2) will overwrite
        if (t + 2 < NTILES) STAGE(t + 2, ((t + 2) % 3) * BUFB);

        evS  = *reinterpret_cast<const float*>(smem + E2L + t * 128 + l31 * 4);
        orvS = (unsigned)((t << 5) | l31);
        const char* bb = smem + (t % 3) * BUFB + l31 * 256;

        c0v = (f16v){}; c1v = (f16v){};
        __builtin_amdgcn_s_setprio(1);
        #pragma unroll
        for (int ks = 0; ks < 4; ++ks) {
            const int cc0 = (4 * ks + 2 * hi) ^ sx;
            const int cc1 = (4 * ks + 2 * hi + 1) ^ sx;
            const i4v lo  = *reinterpret_cast<const i4v*>(bb + (cc0 << 4));
            const i4v hi4 = *reinterpret_cast<const i4v*>(bb + (cc1 << 4));
            const i8v bf = (i8v){lo.x, lo.y, lo.z, lo.w, hi4.x, hi4.y, hi4.z, hi4.w};
            c0v = __builtin_amdgcn_mfma_scale_f32_32x32x64_f8f6f4(
                      afr[0][ks], bf, c0v, 0, 0, 0, SCALE_ONE, 0, SCALE_ONE);
            c1v = __builtin_amdgcn_mfma_scale_f32_32x32x64_f8f6f4(
                      afr[1][ks], bf, c1v, 0, 0, 0, SCALE_ONE, 0, SCALE_ONE);
        }
        __builtin_amdgcn_s_setprio(0);
    };

    // EPI: biased score = bias + 8192^2*e2 - 16384*acc (positive, u32-orderable);
    // low 10 mantissa bits replaced by (t<<5)|l31 (perturbation << fp8 noise)
    auto EPI = [&](const f16v& c0v, const f16v& c1v, float evS, unsigned orvS) {
        #pragma unroll
        for (int r = 0; r < 16; ++r) {
            const float s0 = fmaf(-16384.0f, c0v[r], evS);
            mu0[r] = min(mu0[r], (__float_as_uint(s0) & 0xFFFFFC00u) | orvS);
            const float s1 = fmaf(-16384.0f, c1v[r], evS);
            mu1[r] = min(mu1[r], (__float_as_uint(s1) & 0xFFFFFC00u) | orvS);
        }
    };

    // 2-phase pipeline over NTILES (=32, even): A/B named acc sets alternate.
    f16v aA0, aA1, aB0, aB1;
    float evA, evB; unsigned orvA, orvB;
    PHASE(0, aA0, aA1, evA, orvA);
    for (int t = 1; t < NTILES - 1; t += 2) {
        PHASE(t,     aB0, aB1, evB, orvB);  EPI(aA0, aA1, evA, orvA);
        PHASE(t + 1, aA0, aA1, evA, orvA);  EPI(aB0, aB1, evB, orvB);
    }
    PHASE(NTILES - 1, aB0, aB1, evB, orvB);
    EPI(aA0, aA1, evA, orvA);
    EPI(aB0, aB1, evB, orvB);

    // ---- reduce over 32 col-lanes (butterfly min_u32), then atomicMin ----
    #pragma unroll
    for (int mr = 0; mr < 2; ++mr)
        #pragma unroll
        for (int r = 0; r < 16; ++r) {
            unsigned u = mr ? mu1[r] : mu0[r];
            #pragma unroll
            for (int m = 1; m <= 16; m <<= 1)
                u = min(u, (unsigned)__shfl_xor((int)u, m, 64));
            if (l31 == 0) {
                const int row_g = row0 + w * 64 + mr * 32 + (r & 3) + 8 * (r >> 2) + 4 * hi;
                const int col = cb0 + (int)(u & 1023u);   // (t<<5)|l31 == local col
                const unsigned long long key = ((unsigned long long)u << 32) | (unsigned)col;
                atomicMin(&amin[row_g], key);
            }
        }
}

// ---------- kernel 4: gather + straight-through output + loss ----------
// Loss is linear in block partials: each block atomicAdds its scaled partial
// directly into out[OUT0_ELEMS] (zeroed by k_prep). No fence/ticket/finalize.
__global__ void __launch_bounds__(256)
k_gather_loss(const float* __restrict__ x, const float* __restrict__ cb,
              const unsigned long long* __restrict__ amin, float* __restrict__ out) {
    __shared__ float q[32][257];
    __shared__ int e_s[32];
    const int tid = threadIdx.x;
    const int hw0 = (blockIdx.x & 31) * 32;
    const int b   = blockIdx.x >> 5;
    const int n0  = (b << 10) + hw0;
    if (tid < 32) e_s[tid] = (int)(amin[n0 + tid] & 0xFFFFFFFFu);
    __syncthreads();
    #pragma unroll 8
    for (int r = 0; r < 32; ++r)
        q[r][tid] = cb[(size_t)e_s[r] * EMBED_DIM + tid];
    __syncthreads();
    const int tx = tid & 31;    // hw offset within tile
    const int ty = tid >> 5;    // 0..7  (channel group)
    float sum = 0.f;
    #pragma unroll
    for (int i = 0; i < 32; ++i) {
        const int c = ty * 32 + i;
        const float qv = q[tx][c];
        const int o = ((b * EMBED_DIM + c) << 10) + hw0 + tx;
        const float xv = x[o];
        out[o] = qv;
        const float d = qv - xv;
        sum = fmaf(d, d, sum);
    }
    #pragma unroll
    for (int off = 32; off > 0; off >>= 1) sum += __shfl_down(sum, off, 64);
    __shared__ float ls[4];
    const int lane = tid & 63, wid = tid >> 6;
    if (lane == 0) ls[wid] = sum;
    __syncthreads();
    if (tid == 0)
        atomicAdd(out + OUT0_ELEMS,
                  (ls[0] + ls[1] + ls[2] + ls[3]) * (1.25f / (float)OUT0_ELEMS));
}

extern "C" void kernel_launch(void* const* d_in, const int* in_sizes, int n_in,
                              void* d_out, int out_size, void* d_ws, size_t ws_size,
                              hipStream_t stream) {
    const float* x  = (const float*)d_in[0];
    const float* cb = (const float*)d_in[1];
    float* out = (float*)d_out;

    char* ws = (char*)d_ws;
    unsigned char* xq = (unsigned char*)(ws + WS_XQ);
    unsigned char* eq = (unsigned char*)(ws + WS_EQ);
    float* e2 = (float*)(ws + WS_E2);
    unsigned long long* amin = (unsigned long long*)(ws + WS_AMIN);

    k_prep<<<dim3(32, 8, 17), dim3(32, 8, 1), 0, stream>>>(x, cb, xq, eq, e2, amin, out);
    k_argmin<<<dim3(64 * NSPLIT), dim3(256), SMEM3, stream>>>(xq, eq, e2, amin);
    k_gather_loss<<<dim3(512), dim3(256), 0, stream>>>(x, cb, amin, out);
}